// Round 1
// 261.886 us; speedup vs baseline: 1.0308x; 1.0308x over previous
//
#include <hip/hip_runtime.h>
#include <math.h>

// Bulk zero-write is done by hipMemsetAsync (the rocclr fillBufferAligned
// path, measured in this harness at 6.4 TB/s = 80% of HBM peak — faster than
// our hand-rolled float4 fill at ~5.5 TB/s). This single small kernel then:
//   (a) writes the diagonal 1.0f entries (grid-stride over rows), skipping
//       rows conn_i / conn_j so there is exactly one writer per location, and
//   (b) thread 0 writes the closed-form exp(i*H) 2x2 Hermitian block.
// Layout derived on-device from Np: stride = out_size/N floats per row;
// mult = stride/N is 1 (real matrix) or 2 (interleaved complex).
__global__ __launch_bounds__(256) void diag_patch_kernel(
    float* __restrict__ out, int out_size,
    const float* __restrict__ bii,
    const float* __restrict__ bjj,
    const float* __restrict__ bij_real,
    const float* __restrict__ bij_img,
    const int* __restrict__ conn_i,
    const int* __restrict__ conn_j,
    const int* __restrict__ Np)
{
    const int n = Np[0];                 // wave-uniform scalar load
    const int stride = out_size / n;     // floats per row (N or 2N)
    const int mult = stride / n;         // 1 (real) or 2 (complex interleaved)

    const int i = conn_i[0];
    const int j = conn_j[0];

    const int gid = blockIdx.x * blockDim.x + threadIdx.x;
    const int nth = gridDim.x * blockDim.x;

    // Diagonal ones. Rows i and j get their diagonal from the patch below
    // (single writer per address — no ordering/race concern).
    for (int r = gid; r < n; r += nth) {
        if (r != i && r != j) {
            out[(size_t)r * stride + (size_t)mult * r] = 1.0f;
        }
    }

    if (gid != 0) return;

    // Closed-form exp(i*H) for Hermitian 2x2 H = [[a, c], [conj(c), b]]:
    //   t = (a+b)/2, d = (a-b)/2, r = sqrt(d^2 + |c|^2)
    //   exp(iH) = e^{it} (cos(r) I + i sinc(r) (H - t I))
    const float a  = bii[0];
    const float b  = bjj[0];
    const float cr = bij_real[0];
    const float ci = bij_img[0];

    const float t = 0.5f * (a + b);
    const float d = 0.5f * (a - b);
    const float r = sqrtf(d * d + cr * cr + ci * ci);
    const float sinc = (r > 0.f) ? (sinf(r) / r) : 1.0f;
    const float cosr = cosf(r);
    const float pr = cosf(t);   // phase = exp(i t)
    const float pi = sinf(t);

    const float sd = sinc * d;
    const float eii_r = pr * cosr - pi * sd;
    const float eii_i = pr * sd + pi * cosr;
    const float ejj_r = pr * cosr + pi * sd;
    const float ejj_i = -pr * sd + pi * cosr;
    const float sc_r = -sinc * ci;          // i*sinc*c     = (-sinc*ci, sinc*cr)
    const float sc_i = sinc * cr;
    const float eij_r = pr * sc_r - pi * sc_i;
    const float eij_i = pr * sc_i + pi * sc_r;
    const float sj_r = sinc * ci;           // i*sinc*conj(c) = (sinc*ci, sinc*cr)
    const float sj_i = sinc * cr;
    const float eji_r = pr * sj_r - pi * sj_i;
    const float eji_i = pr * sj_i + pi * sj_r;

    // Write order ii, jj, ij, ji: matches last-wins semantics if i == j.
    if (mult == 2) {  // interleaved complex
        size_t idx;
        idx = (size_t)i * stride + 2 * (size_t)i; out[idx] = eii_r; out[idx + 1] = eii_i;
        idx = (size_t)j * stride + 2 * (size_t)j; out[idx] = ejj_r; out[idx + 1] = ejj_i;
        idx = (size_t)i * stride + 2 * (size_t)j; out[idx] = eij_r; out[idx + 1] = eij_i;
        idx = (size_t)j * stride + 2 * (size_t)i; out[idx] = eji_r; out[idx + 1] = eji_i;
    } else {          // real-only matrix
        out[(size_t)i * stride + i] = eii_r;
        out[(size_t)j * stride + j] = ejj_r;
        out[(size_t)i * stride + j] = eij_r;
        out[(size_t)j * stride + i] = eji_r;
    }
}

extern "C" void kernel_launch(void* const* d_in, const int* in_sizes, int n_in,
                              void* d_out, int out_size, void* d_ws, size_t ws_size,
                              hipStream_t stream) {
    const float* bii      = (const float*)d_in[0];
    const float* bjj      = (const float*)d_in[1];
    const float* bij_real = (const float*)d_in[2];
    const float* bij_img  = (const float*)d_in[3];
    const int*   conn_i   = (const int*)d_in[4];
    const int*   conn_j   = (const int*)d_in[5];
    const int*   Np       = (const int*)d_in[6];

    float* out = (float*)d_out;

    // Bulk zero: runtime memset path (graph-capturable as a memset node),
    // measured at 80% of HBM peak in this harness.
    hipMemsetAsync(d_out, 0, (size_t)out_size * sizeof(float), stream);

    // One small kernel: diagonal ones + 2x2 block patch.
    diag_patch_kernel<<<dim3(64), dim3(256), 0, stream>>>(
        out, out_size, bii, bjj, bij_real, bij_img, conn_i, conn_j, Np);
}